// Round 7
// baseline (1302.406 us; speedup 1.0000x reference)
//
#include <hip/hip_runtime.h>

#define N_NODES 50000
#define N_EDGES 600000
#define F_NODE 128
#define F_EDGE 32
#define MSG 32
#define NPB 64          // nodes per fused block
#define QBLOCKS ((N_NODES + NPB - 1) / NPB)        // 782
#define CBLOCKS ((N_EDGES + 255) / 256)            // 2344

// bf16 helpers
__device__ __forceinline__ unsigned short f2bf(float f) {
    union { float f; unsigned int u; } v; v.f = f;
    unsigned int r = v.u + 0x7fffu + ((v.u >> 16) & 1u);
    return (unsigned short)(r >> 16);
}

// ---------------------------------------------------------------------------
// qcount: blocks [0,QBLOCKS) compute Q[n] = nf[n] @ We[128:256] -> bf16;
// blocks [QBLOCKS,..) do the degree histogram. (round-6 proven)
// ---------------------------------------------------------------------------
__global__ __launch_bounds__(256)
void qcount_kernel(const float* __restrict__ nf,
                   const float* __restrict__ We,     // [288][32]
                   const int* __restrict__ idx,      // [2][E]
                   unsigned short* __restrict__ Q,   // [N][32] bf16
                   int* __restrict__ deg)
{
    if (blockIdx.x >= QBLOCKS) {
        int e = (blockIdx.x - QBLOCKS) * 256 + threadIdx.x;
        if (e < N_EDGES) {
            int n = idx[e];
            if ((unsigned)n < (unsigned)N_NODES) atomicAdd(&deg[n], 1);
        }
        return;
    }
    __shared__ float sInT[32 * 64];
    __shared__ float sWeC[32 * 32];

    const int tid = threadIdx.x;
    const int n0b = blockIdx.x * NPB;
    const int ng = tid & 31;
    const int og = tid >> 5;

    float accp[2][4];
#pragma unroll
    for (int i = 0; i < 2; ++i)
#pragma unroll
        for (int j = 0; j < 4; ++j) accp[i][j] = 0.f;

    for (int kc = 0; kc < 4; ++kc) {
        __syncthreads();
        ((float4*)sWeC)[tid] = ((const float4*)(We + (128 + kc * 32) * MSG))[tid];
        {
            int nl = tid >> 2, q = tid & 3;
            int n = n0b + nl; if (n >= N_NODES) n = N_NODES - 1;
            const float4* src4 = (const float4*)(nf + (size_t)n * F_NODE + kc * 32);
#pragma unroll
            for (int h = 0; h < 2; ++h) {
                float4 v = src4[q * 2 + h];
                int kl = q * 8 + h * 4;
                sInT[(kl + 0) * 64 + nl] = v.x;
                sInT[(kl + 1) * 64 + nl] = v.y;
                sInT[(kl + 2) * 64 + nl] = v.z;
                sInT[(kl + 3) * 64 + nl] = v.w;
            }
        }
        __syncthreads();
#pragma unroll
        for (int k = 0; k < 32; ++k) {
            float2 m = *(const float2*)&sInT[k * 64 + 2 * ng];
            float4 w = *(const float4*)&sWeC[k * 32 + og * 4];
            accp[0][0] += m.x * w.x; accp[0][1] += m.x * w.y;
            accp[0][2] += m.x * w.z; accp[0][3] += m.x * w.w;
            accp[1][0] += m.y * w.x; accp[1][1] += m.y * w.y;
            accp[1][2] += m.y * w.z; accp[1][3] += m.y * w.w;
        }
    }
#pragma unroll
    for (int i = 0; i < 2; ++i) {
        int n = n0b + 2 * ng + i;
        if (n < N_NODES) {
            ushort4 o;
            o.x = f2bf(accp[i][0]); o.y = f2bf(accp[i][1]);
            o.z = f2bf(accp[i][2]); o.w = f2bf(accp[i][3]);
            *(ushort4*)(Q + (size_t)n * MSG + og * 4) = o;
        }
    }
}

// ---------------------------------------------------------------------------
// scan: in-place exclusive (deg -> start offsets), 1 block x 1024. (proven)
// ---------------------------------------------------------------------------
__global__ __launch_bounds__(1024)
void scan_kernel(int* __restrict__ deg_cursor) {
    __shared__ int part[1024];
    const int t = threadIdx.x;
    const int CH = (N_NODES + 1023) / 1024;   // 49
    int lo = t * CH; if (lo > N_NODES) lo = N_NODES;
    int hi = lo + CH; if (hi > N_NODES) hi = N_NODES;
    int s = 0;
    for (int i = lo; i < hi; ++i) s += deg_cursor[i];
    part[t] = s;
    __syncthreads();
    for (int d = 1; d < 1024; d <<= 1) {
        int v = (t >= d) ? part[t - d] : 0;
        __syncthreads();
        part[t] += v;
        __syncthreads();
    }
    int run = (t > 0) ? part[t - 1] : 0;
    for (int i = lo; i < hi; ++i) {
        int d = deg_cursor[i];
        deg_cursor[i] = run;
        run += d;
    }
}

// ---------------------------------------------------------------------------
// scatter: edge ids into destination-sorted order; cursor[n] -> end offset.
// ---------------------------------------------------------------------------
__global__ void scatter_kernel(const int* __restrict__ idx, int* __restrict__ cursor,
                               int* __restrict__ perm) {
    int e = blockIdx.x * 256 + threadIdx.x;
    if (e < N_EDGES) {
        int n = idx[e];
        if ((unsigned)n >= (unsigned)N_NODES) n = 0;
        int p = atomicAdd(&cursor[n], 1);
        if ((unsigned)p < (unsigned)N_EDGES) perm[p] = e;
    }
}

// ---------------------------------------------------------------------------
// Fused kernel. One block = 64 nodes + all their incoming edges.
// Phase 0: P0[n]=nf[n]@We[0:128]+be -> LDS fp32 [64][36] (tiled, proven).
// Edge loop: PER-LANE, NO BARRIERS. lane=edge: ef row (8xfloat4) + Q[n1]
//   (4xuint4 bf16) + P0 (LDS) -> acc[32]; K=32 FMA loop with We_bot from LDS
//   (wave-uniform broadcast); relu; 32 ds_add into sMsgAcc[64][33].
// Phase 2: node GEMM out=relu([nf|msg]@Wn+bn), msg from LDS (round-4 proven).
// LDS = 24 + 4 + 9 + 8.25 = ~45.5 KB -> 3 blocks/CU.
// ---------------------------------------------------------------------------
__global__ __launch_bounds__(256, 3)
void fused_kernel(const float* __restrict__ nf,
                  const int* __restrict__ idx,      // [2][E]
                  const float* __restrict__ ef,     // [E][32]
                  const float* __restrict__ We,     // [288][32]
                  const float* __restrict__ be,     // [32]
                  const float* __restrict__ Wn,     // [160][128]
                  const float* __restrict__ bn,     // [128]
                  const int* __restrict__ perm,     // [E] sorted edge ids
                  const int* __restrict__ cursor,   // [N] end offsets
                  const unsigned short* __restrict__ Q,  // [N][32] bf16
                  float* __restrict__ out)          // [N][128]
{
    __shared__ float sA[32 * 64 + 32 * 128];  // sInT | sWn (phases 0 & 2)
    __shared__ float sWeC[32 * 32];           // phase-0 chunks, then We_bot
    __shared__ float sP0[NPB * 36];           // fp32, stride 36 (16B-aligned)
    __shared__ float sMsgAcc[NPB * 33];

    const int tid = threadIdx.x;
    const int n0b = blockIdx.x * NPB;
    const int nEnd = (n0b + NPB < N_NODES) ? (n0b + NPB) : N_NODES;

    for (int i = tid; i < NPB * 33; i += 256) sMsgAcc[i] = 0.f;

    int rs = (n0b == 0) ? 0 : cursor[n0b - 1];
    int re = cursor[nEnd - 1];
    if (rs < 0) rs = 0;
    if (re > N_EDGES) re = N_EDGES;
    if (rs > re) rs = re;

    float* sInT = sA;          // [32][64]
    float* sWn  = sA + 2048;   // [32][128]

    // ================= Phase 0: P0 = nf@We[0:128] + be (fp32) =============
    {
        const int ng = tid & 31, og0 = tid >> 5;
        float accp[2][4];
#pragma unroll
        for (int i = 0; i < 2; ++i)
#pragma unroll
            for (int j = 0; j < 4; ++j) accp[i][j] = 0.f;

        for (int kc = 0; kc < 4; ++kc) {
            __syncthreads();
            ((float4*)sWeC)[tid] = ((const float4*)(We + kc * 32 * MSG))[tid];
            {
                int nl = tid >> 2, q = tid & 3;
                int n = n0b + nl; if (n >= N_NODES) n = N_NODES - 1;
                const float4* src4 = (const float4*)(nf + (size_t)n * F_NODE + kc * 32);
#pragma unroll
                for (int h = 0; h < 2; ++h) {
                    float4 v = src4[q * 2 + h];
                    int kl = q * 8 + h * 4;
                    sInT[(kl + 0) * 64 + nl] = v.x;
                    sInT[(kl + 1) * 64 + nl] = v.y;
                    sInT[(kl + 2) * 64 + nl] = v.z;
                    sInT[(kl + 3) * 64 + nl] = v.w;
                }
            }
            __syncthreads();
#pragma unroll
            for (int k = 0; k < 32; ++k) {
                float2 m = *(const float2*)&sInT[k * 64 + 2 * ng];
                float4 w = *(const float4*)&sWeC[k * 32 + og0 * 4];
                accp[0][0] += m.x * w.x; accp[0][1] += m.x * w.y;
                accp[0][2] += m.x * w.z; accp[0][3] += m.x * w.w;
                accp[1][0] += m.y * w.x; accp[1][1] += m.y * w.y;
                accp[1][2] += m.y * w.z; accp[1][3] += m.y * w.w;
            }
        }
#pragma unroll
        for (int i = 0; i < 2; ++i)
#pragma unroll
            for (int j = 0; j < 4; ++j)
                sP0[(2 * ng + i) * 36 + og0 * 4 + j] = accp[i][j] + be[og0 * 4 + j];
    }

    __syncthreads();                                   // phase-0 done with sWeC
    ((float4*)sWeC)[tid] = ((const float4*)(We + 256 * MSG))[tid];  // We_bot
    __syncthreads();                                   // We_bot + sP0 visible

    // ================= Edge loop: per-lane, no barriers ===================
    for (int e = rs + tid; e < re; e += 256) {
        int pe = perm[e];
        if ((unsigned)pe >= (unsigned)N_EDGES) pe = 0;          // poison guard
        int n0 = idx[pe];
        int n1 = idx[N_EDGES + pe];
        int ln = n0 - n0b;
        bool lnok = (ln >= 0 && ln < NPB);
        int lnc = lnok ? ln : 0;
        if ((unsigned)n1 >= (unsigned)N_NODES) n1 = 0;          // poison guard

        // issue all global loads up front (latency overlap)
        const float4* ef4 = (const float4*)(ef + (size_t)pe * F_EDGE);
        float4 efr[8];
#pragma unroll
        for (int q = 0; q < 8; ++q) efr[q] = ef4[q];
        const uint4* q4 = (const uint4*)(Q + (size_t)n1 * MSG);
        uint4 qr[4];
#pragma unroll
        for (int q = 0; q < 4; ++q) qr[q] = q4[q];

        // acc = P0[ln] (LDS fp32)
        float acc[32];
#pragma unroll
        for (int jq = 0; jq < 8; ++jq) {
            float4 p = *(const float4*)&sP0[lnc * 36 + jq * 4];
            acc[jq * 4 + 0] = p.x; acc[jq * 4 + 1] = p.y;
            acc[jq * 4 + 2] = p.z; acc[jq * 4 + 3] = p.w;
        }
        // acc += Q[n1] (bf16 unpack: uint t holds cols 2t, 2t+1)
#pragma unroll
        for (int q = 0; q < 4; ++q) {
            unsigned us[4] = { qr[q].x, qr[q].y, qr[q].z, qr[q].w };
#pragma unroll
            for (int h = 0; h < 4; ++h) {
                acc[q * 8 + h * 2 + 0] += __uint_as_float(us[h] << 16);
                acc[q * 8 + h * 2 + 1] += __uint_as_float(us[h] & 0xffff0000u);
            }
        }
        // acc += ef @ We_bot (K=32; We reads are wave-uniform -> broadcast)
#pragma unroll
        for (int kq = 0; kq < 8; ++kq) {
            float av[4] = { efr[kq].x, efr[kq].y, efr[kq].z, efr[kq].w };
#pragma unroll
            for (int c = 0; c < 4; ++c) {
                int k = kq * 4 + c;
                float a = av[c];
#pragma unroll
                for (int jq = 0; jq < 8; ++jq) {
                    float4 w = *(const float4*)&sWeC[k * 32 + jq * 4];
                    acc[jq * 4 + 0] += a * w.x;
                    acc[jq * 4 + 1] += a * w.y;
                    acc[jq * 4 + 2] += a * w.z;
                    acc[jq * 4 + 3] += a * w.w;
                }
            }
        }
        // relu + LDS-atomic accumulate
        if (lnok) {
            float* row = &sMsgAcc[ln * 33];
#pragma unroll
            for (int j = 0; j < 32; ++j) {
                float v = acc[j];
                v = v > 0.f ? v : 0.f;
                atomicAdd(&row[j], v);
            }
        }
    }

    // ================= Phase 2: node GEMM (round-4 proven) ================
    const int ng  = tid & 31;
    const int og2 = tid >> 5;

    float acc2[2][16];
#pragma unroll
    for (int i = 0; i < 2; ++i)
#pragma unroll
        for (int j = 0; j < 16; ++j) acc2[i][j] = 0.f;

    for (int kc = 0; kc < 5; ++kc) {
        __syncthreads();   // kc=0: all edge-loop ds_adds complete
        {
            const float4* w4 = (const float4*)(Wn + (size_t)kc * 32 * 128);
            float4* s4 = (float4*)sWn;
#pragma unroll
            for (int i = 0; i < 4; ++i) s4[tid + 256 * i] = w4[tid + 256 * i];
        }
        {
            int nl = tid >> 2, q = tid & 3;
            if (kc < 4) {
                int n = n0b + nl; if (n >= N_NODES) n = N_NODES - 1;
                const float4* src4 = (const float4*)(nf + (size_t)n * F_NODE + kc * 32);
#pragma unroll
                for (int h = 0; h < 2; ++h) {
                    float4 v = src4[q * 2 + h];
                    int kl = q * 8 + h * 4;
                    sInT[(kl + 0) * 64 + nl] = v.x;
                    sInT[(kl + 1) * 64 + nl] = v.y;
                    sInT[(kl + 2) * 64 + nl] = v.z;
                    sInT[(kl + 3) * 64 + nl] = v.w;
                }
            } else {
#pragma unroll
                for (int h = 0; h < 8; ++h) {
                    int kl = q * 8 + h;
                    sInT[kl * 64 + nl] = sMsgAcc[nl * 33 + kl];
                }
            }
        }
        __syncthreads();

#pragma unroll
        for (int k = 0; k < 32; ++k) {
            float2 m = *(const float2*)&sInT[k * 64 + 2 * ng];
            const float* wr = &sWn[k * 128 + og2 * 16];
            float4 w0 = *(const float4*)&wr[0];
            float4 w1 = *(const float4*)&wr[4];
            float4 w2 = *(const float4*)&wr[8];
            float4 w3 = *(const float4*)&wr[12];
            float ma[2] = { m.x, m.y };
            float wv[16] = { w0.x,w0.y,w0.z,w0.w, w1.x,w1.y,w1.z,w1.w,
                             w2.x,w2.y,w2.z,w2.w, w3.x,w3.y,w3.z,w3.w };
#pragma unroll
            for (int i = 0; i < 2; ++i)
#pragma unroll
                for (int j = 0; j < 16; ++j) acc2[i][j] += ma[i] * wv[j];
        }
    }

    float nbias[16];
#pragma unroll
    for (int j = 0; j < 16; ++j) nbias[j] = bn[og2 * 16 + j];

#pragma unroll
    for (int i = 0; i < 2; ++i) {
        int n = n0b + 2 * ng + i;
        if (n < N_NODES) {
            float* dst = out + (size_t)n * F_NODE + og2 * 16;
#pragma unroll
            for (int j = 0; j < 16; j += 4) {
                float4 v;
                v.x = fmaxf(acc2[i][j + 0] + nbias[j + 0], 0.f);
                v.y = fmaxf(acc2[i][j + 1] + nbias[j + 1], 0.f);
                v.z = fmaxf(acc2[i][j + 2] + nbias[j + 2], 0.f);
                v.w = fmaxf(acc2[i][j + 3] + nbias[j + 3], 0.f);
                *(float4*)(dst + j) = v;
            }
        }
    }
}

extern "C" void kernel_launch(void* const* d_in, const int* in_sizes, int n_in,
                              void* d_out, int out_size, void* d_ws, size_t ws_size,
                              hipStream_t stream) {
    const float* nf  = (const float*)d_in[0];
    const int*   idx = (const int*)d_in[1];
    const float* ef  = (const float*)d_in[2];
    const float* We  = (const float*)d_in[3];
    const float* be  = (const float*)d_in[4];
    const float* Wn  = (const float*)d_in[5];
    const float* bn  = (const float*)d_in[6];
    float* out = (float*)d_out;

    // ws: deg 0.2 MB + perm 2.4 MB + Q bf16 3.2 MB = 5.8 MB
    // (round 6 CONFIRMED this layout runs: fused_q dispatches appeared)
    int* deg_cursor = (int*)d_ws;                          // 50000
    int* perm       = deg_cursor + N_NODES;                // 600000
    unsigned short* Q = (unsigned short*)(perm + N_EDGES); // [N][32] bf16

    hipMemsetAsync(deg_cursor, 0, (size_t)N_NODES * sizeof(int), stream);

    qcount_kernel<<<QBLOCKS + CBLOCKS, 256, 0, stream>>>(nf, We, idx, Q, deg_cursor);
    scan_kernel<<<1, 1024, 0, stream>>>(deg_cursor);
    scatter_kernel<<<CBLOCKS, 256, 0, stream>>>(idx, deg_cursor, perm);

    fused_kernel<<<QBLOCKS, 256, 0, stream>>>(
        nf, idx, ef, We, be, Wn, bn, perm, deg_cursor, Q, out);
}

// Round 8
// 876.404 us; speedup vs baseline: 1.4861x; 1.4861x over previous
//
#include <hip/hip_runtime.h>

#define N_NODES 50000
#define N_EDGES 600000
#define F_NODE 128
#define F_EDGE 32
#define MSG 32
#define NPB 64          // nodes per fused block
#define QBLOCKS ((N_NODES + NPB - 1) / NPB)        // 782
#define CBLOCKS ((N_EDGES + 255) / 256)            // 2344

// bf16 helpers
__device__ __forceinline__ unsigned short f2bf(float f) {
    union { float f; unsigned int u; } v; v.f = f;
    unsigned int r = v.u + 0x7fffu + ((v.u >> 16) & 1u);
    return (unsigned short)(r >> 16);
}

// ---------------------------------------------------------------------------
// qcount: blocks [0,QBLOCKS) compute Q[n] = nf[n] @ We[128:256] -> bf16;
// blocks [QBLOCKS,..) do the degree histogram. (round-6/7 proven)
// ---------------------------------------------------------------------------
__global__ __launch_bounds__(256)
void qcount_kernel(const float* __restrict__ nf,
                   const float* __restrict__ We,     // [288][32]
                   const int* __restrict__ idx,      // [2][E]
                   unsigned short* __restrict__ Q,   // [N][32] bf16
                   int* __restrict__ deg)
{
    if (blockIdx.x >= QBLOCKS) {
        int e = (blockIdx.x - QBLOCKS) * 256 + threadIdx.x;
        if (e < N_EDGES) {
            int n = idx[e];
            if ((unsigned)n < (unsigned)N_NODES) atomicAdd(&deg[n], 1);
        }
        return;
    }
    __shared__ float sInT[32 * 64];
    __shared__ float sWeC[32 * 32];

    const int tid = threadIdx.x;
    const int n0b = blockIdx.x * NPB;
    const int ng = tid & 31;
    const int og = tid >> 5;

    float accp[2][4];
#pragma unroll
    for (int i = 0; i < 2; ++i)
#pragma unroll
        for (int j = 0; j < 4; ++j) accp[i][j] = 0.f;

    for (int kc = 0; kc < 4; ++kc) {
        __syncthreads();
        ((float4*)sWeC)[tid] = ((const float4*)(We + (128 + kc * 32) * MSG))[tid];
        {
            int nl = tid >> 2, q = tid & 3;
            int n = n0b + nl; if (n >= N_NODES) n = N_NODES - 1;
            const float4* src4 = (const float4*)(nf + (size_t)n * F_NODE + kc * 32);
#pragma unroll
            for (int h = 0; h < 2; ++h) {
                float4 v = src4[q * 2 + h];
                int kl = q * 8 + h * 4;
                sInT[(kl + 0) * 64 + nl] = v.x;
                sInT[(kl + 1) * 64 + nl] = v.y;
                sInT[(kl + 2) * 64 + nl] = v.z;
                sInT[(kl + 3) * 64 + nl] = v.w;
            }
        }
        __syncthreads();
#pragma unroll
        for (int k = 0; k < 32; ++k) {
            float2 m = *(const float2*)&sInT[k * 64 + 2 * ng];
            float4 w = *(const float4*)&sWeC[k * 32 + og * 4];
            accp[0][0] += m.x * w.x; accp[0][1] += m.x * w.y;
            accp[0][2] += m.x * w.z; accp[0][3] += m.x * w.w;
            accp[1][0] += m.y * w.x; accp[1][1] += m.y * w.y;
            accp[1][2] += m.y * w.z; accp[1][3] += m.y * w.w;
        }
    }
#pragma unroll
    for (int i = 0; i < 2; ++i) {
        int n = n0b + 2 * ng + i;
        if (n < N_NODES) {
            ushort4 o;
            o.x = f2bf(accp[i][0]); o.y = f2bf(accp[i][1]);
            o.z = f2bf(accp[i][2]); o.w = f2bf(accp[i][3]);
            *(ushort4*)(Q + (size_t)n * MSG + og * 4) = o;
        }
    }
}

// ---------------------------------------------------------------------------
// scan: in-place exclusive (deg -> start offsets), 1 block x 1024. (proven)
// ---------------------------------------------------------------------------
__global__ __launch_bounds__(1024)
void scan_kernel(int* __restrict__ deg_cursor) {
    __shared__ int part[1024];
    const int t = threadIdx.x;
    const int CH = (N_NODES + 1023) / 1024;   // 49
    int lo = t * CH; if (lo > N_NODES) lo = N_NODES;
    int hi = lo + CH; if (hi > N_NODES) hi = N_NODES;
    int s = 0;
    for (int i = lo; i < hi; ++i) s += deg_cursor[i];
    part[t] = s;
    __syncthreads();
    for (int d = 1; d < 1024; d <<= 1) {
        int v = (t >= d) ? part[t - d] : 0;
        __syncthreads();
        part[t] += v;
        __syncthreads();
    }
    int run = (t > 0) ? part[t - 1] : 0;
    for (int i = lo; i < hi; ++i) {
        int d = deg_cursor[i];
        deg_cursor[i] = run;
        run += d;
    }
}

// ---------------------------------------------------------------------------
// scatter: edge ids into destination-sorted order; cursor[n] -> end offset.
// ---------------------------------------------------------------------------
__global__ void scatter_kernel(const int* __restrict__ idx, int* __restrict__ cursor,
                               int* __restrict__ perm) {
    int e = blockIdx.x * 256 + threadIdx.x;
    if (e < N_EDGES) {
        int n = idx[e];
        if ((unsigned)n >= (unsigned)N_NODES) n = 0;
        int p = atomicAdd(&cursor[n], 1);
        if ((unsigned)p < (unsigned)N_EDGES) perm[p] = e;
    }
}

// ---------------------------------------------------------------------------
// Fused kernel. One block = 64 nodes + all their incoming edges.
// Phase 0: P0[n]=nf[n]@We[0:128]+be -> LDS bf16 [64][36]. (round-6 proven)
// Phase 1: round-4's PROVEN wave-tiled chunk loop with ONE K-chunk (ef^T),
//   acc[4][8]/thread. Epilogue is register-tight: edges processed strictly
//   sequentially; per edge only one uint4 (Q row) + two ushort4 (P0) coexist
//   with acc -> peak ~48 VGPRs, below round-4's proven no-spill envelope.
// Phase 2: node GEMM out=relu([nf|msg]@Wn+bn), msg from LDS. (proven)
// LDS = 32 + 4 + 4.5 + 8.25 + 2 = ~50.75 KB -> 3 blocks/CU.
// ---------------------------------------------------------------------------
__global__ __launch_bounds__(256, 3)
void fused_kernel(const float* __restrict__ nf,
                  const int* __restrict__ idx,      // [2][E]
                  const float* __restrict__ ef,     // [E][32]
                  const float* __restrict__ We,     // [288][32]
                  const float* __restrict__ be,     // [32]
                  const float* __restrict__ Wn,     // [160][128]
                  const float* __restrict__ bn,     // [128]
                  const int* __restrict__ perm,     // [E] sorted edge ids
                  const int* __restrict__ cursor,   // [N] end offsets
                  const unsigned short* __restrict__ Q,  // [N][32] bf16
                  float* __restrict__ out)          // [N][128]
{
    __shared__ float sBuf[32 * 256];          // ef^T chunk; ph0/ph2: sInT+sWn
    __shared__ float sWeC[32 * 32];           // ph0 chunks, then We_bot
    __shared__ unsigned short sP0h[NPB * 36]; // bf16, stride 36 (8B-aligned rows)
    __shared__ float sMsgAcc[NPB * 33];
    __shared__ int sLn[256];
    __shared__ int sN1[256];

    const int tid = threadIdx.x;
    const int n0b = blockIdx.x * NPB;
    const int nEnd = (n0b + NPB < N_NODES) ? (n0b + NPB) : N_NODES;

    for (int i = tid; i < NPB * 33; i += 256) sMsgAcc[i] = 0.f;

    int rs = (n0b == 0) ? 0 : cursor[n0b - 1];
    int re = cursor[nEnd - 1];
    if (rs < 0) rs = 0;
    if (re > N_EDGES) re = N_EDGES;
    if (rs > re) rs = re;

    float* sInT = sBuf;          // [32][64]
    float* sWn  = sBuf + 2048;   // [32][128]

    // ================= Phase 0: P0 = nf@We[0:128] + be -> bf16 ============
    {
        const int ng = tid & 31, og0 = tid >> 5;
        float accp[2][4];
#pragma unroll
        for (int i = 0; i < 2; ++i)
#pragma unroll
            for (int j = 0; j < 4; ++j) accp[i][j] = 0.f;

        for (int kc = 0; kc < 4; ++kc) {
            __syncthreads();
            ((float4*)sWeC)[tid] = ((const float4*)(We + kc * 32 * MSG))[tid];
            {
                int nl = tid >> 2, q = tid & 3;
                int n = n0b + nl; if (n >= N_NODES) n = N_NODES - 1;
                const float4* src4 = (const float4*)(nf + (size_t)n * F_NODE + kc * 32);
#pragma unroll
                for (int h = 0; h < 2; ++h) {
                    float4 v = src4[q * 2 + h];
                    int kl = q * 8 + h * 4;
                    sInT[(kl + 0) * 64 + nl] = v.x;
                    sInT[(kl + 1) * 64 + nl] = v.y;
                    sInT[(kl + 2) * 64 + nl] = v.z;
                    sInT[(kl + 3) * 64 + nl] = v.w;
                }
            }
            __syncthreads();
#pragma unroll
            for (int k = 0; k < 32; ++k) {
                float2 m = *(const float2*)&sInT[k * 64 + 2 * ng];
                float4 w = *(const float4*)&sWeC[k * 32 + og0 * 4];
                accp[0][0] += m.x * w.x; accp[0][1] += m.x * w.y;
                accp[0][2] += m.x * w.z; accp[0][3] += m.x * w.w;
                accp[1][0] += m.y * w.x; accp[1][1] += m.y * w.y;
                accp[1][2] += m.y * w.z; accp[1][3] += m.y * w.w;
            }
        }
#pragma unroll
        for (int i = 0; i < 2; ++i)
#pragma unroll
            for (int j = 0; j < 4; ++j)
                sP0h[(2 * ng + i) * 36 + og0 * 4 + j] =
                    f2bf(accp[i][j] + be[og0 * 4 + j]);
    }

    __syncthreads();                                   // ph0 done with sWeC
    ((float4*)sWeC)[tid] = ((const float4*)(We + 256 * MSG))[tid];  // We_bot

    // ================= Phase 1: edge chunks (round-4 skeleton) ============
    const int eg = tid & 63;   // edges 4*eg..+3
    const int og = tid >> 6;   // cols og*8..+7 (wave-uniform)

    for (int cs = rs; cs < re; cs += 256) {
        __syncthreads();   // prev chunk done; We_bot (first iter) visible
        {
            int e = cs + tid;
            int pe = 0, ln = -1, n1 = 0;
            if (e < re) {
                pe = perm[e];
                if ((unsigned)pe >= (unsigned)N_EDGES) pe = 0;   // poison guard
                ln = idx[pe] - n0b;
                if (ln < 0 || ln >= NPB) ln = -1;                // poison guard
                n1 = idx[N_EDGES + pe];
                if ((unsigned)n1 >= (unsigned)N_NODES) n1 = 0;   // poison guard
            }
            sLn[tid] = ln; sN1[tid] = n1;
            const float4* ef4 = (const float4*)(ef + (size_t)pe * F_EDGE);
#pragma unroll
            for (int q = 0; q < 8; ++q) {
                float4 v = ef4[q];
                sBuf[(q * 4 + 0) * 256 + tid] = v.x;
                sBuf[(q * 4 + 1) * 256 + tid] = v.y;
                sBuf[(q * 4 + 2) * 256 + tid] = v.z;
                sBuf[(q * 4 + 3) * 256 + tid] = v.w;
            }
        }
        __syncthreads();

        float acc[4][8];
#pragma unroll
        for (int i = 0; i < 4; ++i)
#pragma unroll
            for (int j = 0; j < 8; ++j) acc[i][j] = 0.f;

        const float* weB = sWeC + og * 8;
#pragma unroll
        for (int k = 0; k < 32; ++k) {
            float4 m = *(const float4*)&sBuf[k * 256 + 4 * eg];   // conflict-free b128
            float4 w0 = *(const float4*)&weB[k * 32];             // broadcast
            float4 w1 = *(const float4*)&weB[k * 32 + 4];
            float ma[4] = { m.x, m.y, m.z, m.w };
            float wv[8] = { w0.x, w0.y, w0.z, w0.w, w1.x, w1.y, w1.z, w1.w };
#pragma unroll
            for (int i = 0; i < 4; ++i)
#pragma unroll
                for (int j = 0; j < 8; ++j) acc[i][j] += ma[i] * wv[j];
        }

        // ---- epilogue: strictly sequential per edge (register-tight) ----
#pragma unroll
        for (int i = 0; i < 4; ++i) {
            int el = 4 * eg + i;
            int ln = sLn[el];
            if (ln < 0) continue;
            int n1 = sN1[el];
            uint4 q = *(const uint4*)(Q + (size_t)n1 * MSG + og * 8);  // 16B, aligned
            ushort4 pa = *(const ushort4*)&sP0h[ln * 36 + og * 8];
            ushort4 pb = *(const ushort4*)&sP0h[ln * 36 + og * 8 + 4];
            float* row = &sMsgAcc[ln * 33 + og * 8];
            unsigned qs[4] = { q.x, q.y, q.z, q.w };
            unsigned short ps[8] = { pa.x, pa.y, pa.z, pa.w, pb.x, pb.y, pb.z, pb.w };
#pragma unroll
            for (int h = 0; h < 4; ++h) {
                float q0 = __uint_as_float(qs[h] << 16);
                float q1 = __uint_as_float(qs[h] & 0xffff0000u);
                float p0 = __uint_as_float(((unsigned)ps[2 * h]) << 16);
                float p1 = __uint_as_float(((unsigned)ps[2 * h + 1]) << 16);
                float v0 = fmaxf(acc[i][2 * h] + p0 + q0, 0.f);
                float v1 = fmaxf(acc[i][2 * h + 1] + p1 + q1, 0.f);
                atomicAdd(&row[2 * h], v0);
                atomicAdd(&row[2 * h + 1], v1);
            }
        }
    }

    // ================= Phase 2: node GEMM (proven) ========================
    const int ng  = tid & 31;
    const int og2 = tid >> 5;

    float acc2[2][16];
#pragma unroll
    for (int i = 0; i < 2; ++i)
#pragma unroll
        for (int j = 0; j < 16; ++j) acc2[i][j] = 0.f;

    for (int kc = 0; kc < 5; ++kc) {
        __syncthreads();   // kc=0: last chunk's epilogue + sBuf reads done
        {
            const float4* w4 = (const float4*)(Wn + (size_t)kc * 32 * 128);
            float4* s4 = (float4*)sWn;
#pragma unroll
            for (int i = 0; i < 4; ++i) s4[tid + 256 * i] = w4[tid + 256 * i];
        }
        {
            int nl = tid >> 2, q = tid & 3;
            if (kc < 4) {
                int n = n0b + nl; if (n >= N_NODES) n = N_NODES - 1;
                const float4* src4 = (const float4*)(nf + (size_t)n * F_NODE + kc * 32);
#pragma unroll
                for (int h = 0; h < 2; ++h) {
                    float4 v = src4[q * 2 + h];
                    int kl = q * 8 + h * 4;
                    sInT[(kl + 0) * 64 + nl] = v.x;
                    sInT[(kl + 1) * 64 + nl] = v.y;
                    sInT[(kl + 2) * 64 + nl] = v.z;
                    sInT[(kl + 3) * 64 + nl] = v.w;
                }
            } else {
#pragma unroll
                for (int h = 0; h < 8; ++h) {
                    int kl = q * 8 + h;
                    sInT[kl * 64 + nl] = sMsgAcc[nl * 33 + kl];
                }
            }
        }
        __syncthreads();

#pragma unroll
        for (int k = 0; k < 32; ++k) {
            float2 m = *(const float2*)&sInT[k * 64 + 2 * ng];
            const float* wr = &sWn[k * 128 + og2 * 16];
            float4 w0 = *(const float4*)&wr[0];
            float4 w1 = *(const float4*)&wr[4];
            float4 w2 = *(const float4*)&wr[8];
            float4 w3 = *(const float4*)&wr[12];
            float ma[2] = { m.x, m.y };
            float wv[16] = { w0.x,w0.y,w0.z,w0.w, w1.x,w1.y,w1.z,w1.w,
                             w2.x,w2.y,w2.z,w2.w, w3.x,w3.y,w3.z,w3.w };
#pragma unroll
            for (int i = 0; i < 2; ++i)
#pragma unroll
                for (int j = 0; j < 16; ++j) acc2[i][j] += ma[i] * wv[j];
        }
    }

    float nbias[16];
#pragma unroll
    for (int j = 0; j < 16; ++j) nbias[j] = bn[og2 * 16 + j];

#pragma unroll
    for (int i = 0; i < 2; ++i) {
        int n = n0b + 2 * ng + i;
        if (n < N_NODES) {
            float* dst = out + (size_t)n * F_NODE + og2 * 16;
#pragma unroll
            for (int j = 0; j < 16; j += 4) {
                float4 v;
                v.x = fmaxf(acc2[i][j + 0] + nbias[j + 0], 0.f);
                v.y = fmaxf(acc2[i][j + 1] + nbias[j + 1], 0.f);
                v.z = fmaxf(acc2[i][j + 2] + nbias[j + 2], 0.f);
                v.w = fmaxf(acc2[i][j + 3] + nbias[j + 3], 0.f);
                *(float4*)(dst + j) = v;
            }
        }
    }
}

extern "C" void kernel_launch(void* const* d_in, const int* in_sizes, int n_in,
                              void* d_out, int out_size, void* d_ws, size_t ws_size,
                              hipStream_t stream) {
    const float* nf  = (const float*)d_in[0];
    const int*   idx = (const int*)d_in[1];
    const float* ef  = (const float*)d_in[2];
    const float* We  = (const float*)d_in[3];
    const float* be  = (const float*)d_in[4];
    const float* Wn  = (const float*)d_in[5];
    const float* bn  = (const float*)d_in[6];
    float* out = (float*)d_out;

    // ws: deg 0.2 MB + perm 2.4 MB + Q bf16 3.2 MB = 5.8 MB (confirmed safe)
    int* deg_cursor = (int*)d_ws;                          // 50000
    int* perm       = deg_cursor + N_NODES;                // 600000
    unsigned short* Q = (unsigned short*)(perm + N_EDGES); // [N][32] bf16

    hipMemsetAsync(deg_cursor, 0, (size_t)N_NODES * sizeof(int), stream);

    qcount_kernel<<<QBLOCKS + CBLOCKS, 256, 0, stream>>>(nf, We, idx, Q, deg_cursor);
    scan_kernel<<<1, 1024, 0, stream>>>(deg_cursor);
    scatter_kernel<<<CBLOCKS, 256, 0, stream>>>(idx, deg_cursor, perm);

    fused_kernel<<<QBLOCKS, 256, 0, stream>>>(
        nf, idx, ef, We, be, Wn, bn, perm, deg_cursor, Q, out);
}

// Round 9
// 376.130 us; speedup vs baseline: 3.4626x; 2.3301x over previous
//
#include <hip/hip_runtime.h>

#define N_NODES 50000
#define N_EDGES 600000
#define F_NODE 128
#define F_EDGE 32
#define MSG 32
#define NPB 64          // nodes per fused block
#define QBLOCKS ((N_NODES + NPB - 1) / NPB)        // 782
#define CBLOCKS ((N_EDGES + 255) / 256)            // 2344

// bf16 helpers
__device__ __forceinline__ unsigned short f2bf(float f) {
    union { float f; unsigned int u; } v; v.f = f;
    unsigned int r = v.u + 0x7fffu + ((v.u >> 16) & 1u);
    return (unsigned short)(r >> 16);
}

// ---------------------------------------------------------------------------
// qcount: blocks [0,QBLOCKS) compute Q[n] = nf[n] @ We[128:256] -> bf16;
// blocks [QBLOCKS,..) do the degree histogram. (round-6/7/8 proven)
// ---------------------------------------------------------------------------
__global__ __launch_bounds__(256)
void qcount_kernel(const float* __restrict__ nf,
                   const float* __restrict__ We,     // [288][32]
                   const int* __restrict__ idx,      // [2][E]
                   unsigned short* __restrict__ Q,   // [N][32] bf16
                   int* __restrict__ deg)
{
    if (blockIdx.x >= QBLOCKS) {
        int e = (blockIdx.x - QBLOCKS) * 256 + threadIdx.x;
        if (e < N_EDGES) {
            int n = idx[e];
            if ((unsigned)n < (unsigned)N_NODES) atomicAdd(&deg[n], 1);
        }
        return;
    }
    __shared__ float sInT[32 * 64];
    __shared__ float sWeC[32 * 32];

    const int tid = threadIdx.x;
    const int n0b = blockIdx.x * NPB;
    const int ng = tid & 31;
    const int og = tid >> 5;

    float accp[2][4];
#pragma unroll
    for (int i = 0; i < 2; ++i)
#pragma unroll
        for (int j = 0; j < 4; ++j) accp[i][j] = 0.f;

    for (int kc = 0; kc < 4; ++kc) {
        __syncthreads();
        ((float4*)sWeC)[tid] = ((const float4*)(We + (128 + kc * 32) * MSG))[tid];
        {
            int nl = tid >> 2, q = tid & 3;
            int n = n0b + nl; if (n >= N_NODES) n = N_NODES - 1;
            const float4* src4 = (const float4*)(nf + (size_t)n * F_NODE + kc * 32);
#pragma unroll
            for (int h = 0; h < 2; ++h) {
                float4 v = src4[q * 2 + h];
                int kl = q * 8 + h * 4;
                sInT[(kl + 0) * 64 + nl] = v.x;
                sInT[(kl + 1) * 64 + nl] = v.y;
                sInT[(kl + 2) * 64 + nl] = v.z;
                sInT[(kl + 3) * 64 + nl] = v.w;
            }
        }
        __syncthreads();
#pragma unroll
        for (int k = 0; k < 32; ++k) {
            float2 m = *(const float2*)&sInT[k * 64 + 2 * ng];
            float4 w = *(const float4*)&sWeC[k * 32 + og * 4];
            accp[0][0] += m.x * w.x; accp[0][1] += m.x * w.y;
            accp[0][2] += m.x * w.z; accp[0][3] += m.x * w.w;
            accp[1][0] += m.y * w.x; accp[1][1] += m.y * w.y;
            accp[1][2] += m.y * w.z; accp[1][3] += m.y * w.w;
        }
    }
#pragma unroll
    for (int i = 0; i < 2; ++i) {
        int n = n0b + 2 * ng + i;
        if (n < N_NODES) {
            ushort4 o;
            o.x = f2bf(accp[i][0]); o.y = f2bf(accp[i][1]);
            o.z = f2bf(accp[i][2]); o.w = f2bf(accp[i][3]);
            *(ushort4*)(Q + (size_t)n * MSG + og * 4) = o;
        }
    }
}

// ---------------------------------------------------------------------------
// scan: in-place exclusive (deg -> start offsets), 1 block x 1024. (proven)
// ---------------------------------------------------------------------------
__global__ __launch_bounds__(1024)
void scan_kernel(int* __restrict__ deg_cursor) {
    __shared__ int part[1024];
    const int t = threadIdx.x;
    const int CH = (N_NODES + 1023) / 1024;   // 49
    int lo = t * CH; if (lo > N_NODES) lo = N_NODES;
    int hi = lo + CH; if (hi > N_NODES) hi = N_NODES;
    int s = 0;
    for (int i = lo; i < hi; ++i) s += deg_cursor[i];
    part[t] = s;
    __syncthreads();
    for (int d = 1; d < 1024; d <<= 1) {
        int v = (t >= d) ? part[t - d] : 0;
        __syncthreads();
        part[t] += v;
        __syncthreads();
    }
    int run = (t > 0) ? part[t - 1] : 0;
    for (int i = lo; i < hi; ++i) {
        int d = deg_cursor[i];
        deg_cursor[i] = run;
        run += d;
    }
}

// ---------------------------------------------------------------------------
// scatter: edge ids into destination-sorted order; cursor[n] -> end offset.
// ---------------------------------------------------------------------------
__global__ void scatter_kernel(const int* __restrict__ idx, int* __restrict__ cursor,
                               int* __restrict__ perm) {
    int e = blockIdx.x * 256 + threadIdx.x;
    if (e < N_EDGES) {
        int n = idx[e];
        if ((unsigned)n >= (unsigned)N_NODES) n = 0;
        int p = atomicAdd(&cursor[n], 1);
        if ((unsigned)p < (unsigned)N_EDGES) perm[p] = e;
    }
}

// ---------------------------------------------------------------------------
// Fused kernel — ZERO atomics. One block = 64 nodes + all their edges.
// Phase 0: P0[n]=nf[n]@We[0:128]+be -> LDS bf16 [64][40] (16B-aligned rows).
// Chunk loop (256 edges, 4 barriers):
//   stage: perm (coalesced) + n1 gather + per-edge ln via binary search in
//          sOff[65] + ef^T -> sBuf. (no idx[pe] gather)
//   compute: proven K=32 GEMM, acc[4][8].
//   store: +P0(LDS) +Q(16B gather) +relu -> sBuf as msgT[col][256], float4
//          along edges (16B-aligned, conflict-free).
//   reduce: thread(node,colgrp) sums its node's contiguous edge range into
//          msum[8] registers. Plain LDS reads. No atomics.
// Phase 2: node GEMM; kc=4 staging writes msum regs directly (same mapping).
// LDS = 32 + 4 + 5 + 0.26 + 2 = ~43.3 KB -> 3 blocks/CU.
// ---------------------------------------------------------------------------
__global__ __launch_bounds__(256, 3)
void fused_kernel(const float* __restrict__ nf,
                  const int* __restrict__ idx,      // [2][E]
                  const float* __restrict__ ef,     // [E][32]
                  const float* __restrict__ We,     // [288][32]
                  const float* __restrict__ be,     // [32]
                  const float* __restrict__ Wn,     // [160][128]
                  const float* __restrict__ bn,     // [128]
                  const int* __restrict__ perm,     // [E] sorted edge ids
                  const int* __restrict__ cursor,   // [N] end offsets
                  const unsigned short* __restrict__ Q,  // [N][32] bf16
                  float* __restrict__ out)          // [N][128]
{
    __shared__ float sBuf[32 * 256];          // ef^T / msgT / (sInT|sWn)
    __shared__ float sWeC[32 * 32];           // ph0 chunks, then We_bot
    __shared__ unsigned short sP0h[NPB * 40]; // bf16, stride 40 (16B rows)
    __shared__ int sOff[NPB + 1];
    __shared__ int sLn[256];
    __shared__ int sN1[256];

    const int tid = threadIdx.x;
    const int n0b = blockIdx.x * NPB;

    // per-node start offsets: sOff[i] = start of node n0b+i; sOff[NPB] = end
    if (tid <= NPB) {
        int nn = n0b + tid - 1;
        int v;
        if (nn < 0) v = 0;
        else { if (nn >= N_NODES) nn = N_NODES - 1; v = cursor[nn]; }
        if (v < 0) v = 0;
        if (v > N_EDGES) v = N_EDGES;
        sOff[tid] = v;
    }

    float* sInT = sBuf;          // [32][64]
    float* sWn  = sBuf + 2048;   // [32][128]

    // ================= Phase 0: P0 = nf@We[0:128] + be -> bf16 ============
    {
        const int ng = tid & 31, og0 = tid >> 5;
        float accp[2][4];
#pragma unroll
        for (int i = 0; i < 2; ++i)
#pragma unroll
            for (int j = 0; j < 4; ++j) accp[i][j] = 0.f;

        for (int kc = 0; kc < 4; ++kc) {
            __syncthreads();
            ((float4*)sWeC)[tid] = ((const float4*)(We + kc * 32 * MSG))[tid];
            {
                int nl = tid >> 2, q = tid & 3;
                int n = n0b + nl; if (n >= N_NODES) n = N_NODES - 1;
                const float4* src4 = (const float4*)(nf + (size_t)n * F_NODE + kc * 32);
#pragma unroll
                for (int h = 0; h < 2; ++h) {
                    float4 v = src4[q * 2 + h];
                    int kl = q * 8 + h * 4;
                    sInT[(kl + 0) * 64 + nl] = v.x;
                    sInT[(kl + 1) * 64 + nl] = v.y;
                    sInT[(kl + 2) * 64 + nl] = v.z;
                    sInT[(kl + 3) * 64 + nl] = v.w;
                }
            }
            __syncthreads();
#pragma unroll
            for (int k = 0; k < 32; ++k) {
                float2 m = *(const float2*)&sInT[k * 64 + 2 * ng];
                float4 w = *(const float4*)&sWeC[k * 32 + og0 * 4];
                accp[0][0] += m.x * w.x; accp[0][1] += m.x * w.y;
                accp[0][2] += m.x * w.z; accp[0][3] += m.x * w.w;
                accp[1][0] += m.y * w.x; accp[1][1] += m.y * w.y;
                accp[1][2] += m.y * w.z; accp[1][3] += m.y * w.w;
            }
        }
#pragma unroll
        for (int i = 0; i < 2; ++i)
#pragma unroll
            for (int j = 0; j < 4; ++j)
                sP0h[(2 * ng + i) * 40 + og0 * 4 + j] =
                    f2bf(accp[i][j] + be[og0 * 4 + j]);
    }

    __syncthreads();                                   // ph0 done with sWeC
    ((float4*)sWeC)[tid] = ((const float4*)(We + 256 * MSG))[tid];  // We_bot

    const int rs = sOff[0];
    const int re = sOff[NPB];

    // persistent per-thread message sums: thread = (node rnl, cols rq8..+7)
    float msum[8];
#pragma unroll
    for (int j = 0; j < 8; ++j) msum[j] = 0.f;
    const int rnl = tid >> 2;
    const int rq8 = (tid & 3) * 8;

    const int eg = tid & 63;   // edges 4*eg..+3
    const int og = tid >> 6;   // cols og*8..+7 (wave-uniform)

    // ================= Chunk loop =========================================
    for (int cs = rs; cs < re; cs += 256) {
        __syncthreads();   // (A) prev reduction reads done; We_bot visible
        {
            int e = cs + tid;
            int pe = 0, n1 = 0, ln = 0;
            if (e < re) {
                pe = perm[e];
                if ((unsigned)pe >= (unsigned)N_EDGES) pe = 0;   // poison guard
                n1 = idx[N_EDGES + pe];
                if ((unsigned)n1 >= (unsigned)N_NODES) n1 = 0;   // poison guard
                int lo = 0, hi = NPB;                            // ln: binary search
#pragma unroll
                for (int s = 0; s < 6; ++s) {
                    int mid = (lo + hi) >> 1;
                    if (sOff[mid] <= e) lo = mid; else hi = mid;
                }
                ln = lo;
            }
            sLn[tid] = ln; sN1[tid] = n1;
            const float4* ef4 = (const float4*)(ef + (size_t)pe * F_EDGE);
#pragma unroll
            for (int q = 0; q < 8; ++q) {
                float4 v = ef4[q];
                sBuf[(q * 4 + 0) * 256 + tid] = v.x;
                sBuf[(q * 4 + 1) * 256 + tid] = v.y;
                sBuf[(q * 4 + 2) * 256 + tid] = v.z;
                sBuf[(q * 4 + 3) * 256 + tid] = v.w;
            }
        }
        __syncthreads();   // (B) staging visible

        float acc[4][8];
#pragma unroll
        for (int i = 0; i < 4; ++i)
#pragma unroll
            for (int j = 0; j < 8; ++j) acc[i][j] = 0.f;

        const float* weB = sWeC + og * 8;
#pragma unroll
        for (int k = 0; k < 32; ++k) {
            float4 m = *(const float4*)&sBuf[k * 256 + 4 * eg];   // conflict-free b128
            float4 w0 = *(const float4*)&weB[k * 32];             // broadcast
            float4 w1 = *(const float4*)&weB[k * 32 + 4];
            float ma[4] = { m.x, m.y, m.z, m.w };
            float wv[8] = { w0.x, w0.y, w0.z, w0.w, w1.x, w1.y, w1.z, w1.w };
#pragma unroll
            for (int i = 0; i < 4; ++i)
#pragma unroll
                for (int j = 0; j < 8; ++j) acc[i][j] += ma[i] * wv[j];
        }

        __syncthreads();   // (C) all ef^T reads done; sBuf reusable

        // ---- +P0 +Q, relu, store msgT[col][edge] (b128 along edges) ----
        {
            uint4 qv[4], pv[4];
#pragma unroll
            for (int i = 0; i < 4; ++i) {
                int el = 4 * eg + i;
                int n1 = sN1[el];
                int ln = sLn[el];
                qv[i] = *(const uint4*)(Q + (size_t)n1 * MSG + og * 8);
                pv[i] = *(const uint4*)((const unsigned short*)sP0h + ln * 40 + og * 8);
            }
#pragma unroll
            for (int j = 0; j < 8; ++j) {
                float4 s;
                float sv[4];
#pragma unroll
                for (int i = 0; i < 4; ++i) {
                    unsigned qu = ((const unsigned*)&qv[i])[j >> 1];
                    unsigned pu = ((const unsigned*)&pv[i])[j >> 1];
                    float qf = __uint_as_float((j & 1) ? (qu & 0xffff0000u) : (qu << 16));
                    float pf = __uint_as_float((j & 1) ? (pu & 0xffff0000u) : (pu << 16));
                    sv[i] = fmaxf(acc[i][j] + pf + qf, 0.f);
                }
                s.x = sv[0]; s.y = sv[1]; s.z = sv[2]; s.w = sv[3];
                *(float4*)&sBuf[(og * 8 + j) * 256 + 4 * eg] = s;   // aligned, conflict-free
            }
        }
        __syncthreads();   // (D) msgT visible

        // ---- segmented reduction (no atomics): my node's range this chunk
        {
            int lo = sOff[rnl] - cs;     if (lo < 0) lo = 0;
            int hi = sOff[rnl + 1] - cs; if (hi > 256) hi = 256;
            for (int el = lo; el < hi; ++el) {
#pragma unroll
                for (int j = 0; j < 8; ++j)
                    msum[j] += sBuf[(rq8 + j) * 256 + el];
            }
        }
    }

    // ================= Phase 2: node GEMM (proven; kc=4 from msum) ========
    const int ng  = tid & 31;
    const int og2 = tid >> 5;

    float acc2[2][16];
#pragma unroll
    for (int i = 0; i < 2; ++i)
#pragma unroll
        for (int j = 0; j < 16; ++j) acc2[i][j] = 0.f;

    for (int kc = 0; kc < 5; ++kc) {
        __syncthreads();   // kc=0: last reduction reads done
        {
            const float4* w4 = (const float4*)(Wn + (size_t)kc * 32 * 128);
            float4* s4 = (float4*)sWn;
#pragma unroll
            for (int i = 0; i < 4; ++i) s4[tid + 256 * i] = w4[tid + 256 * i];
        }
        {
            int nl = tid >> 2, q = tid & 3;
            if (kc < 4) {
                int n = n0b + nl; if (n >= N_NODES) n = N_NODES - 1;
                const float4* src4 = (const float4*)(nf + (size_t)n * F_NODE + kc * 32);
#pragma unroll
                for (int h = 0; h < 2; ++h) {
                    float4 v = src4[q * 2 + h];
                    int kl = q * 8 + h * 4;
                    sInT[(kl + 0) * 64 + nl] = v.x;
                    sInT[(kl + 1) * 64 + nl] = v.y;
                    sInT[(kl + 2) * 64 + nl] = v.z;
                    sInT[(kl + 3) * 64 + nl] = v.w;
                }
            } else {
                // thread (nl, q) owns exactly msum for node nl, cols q*8..+7
#pragma unroll
                for (int h = 0; h < 8; ++h)
                    sInT[(q * 8 + h) * 64 + nl] = msum[h];
            }
        }
        __syncthreads();

#pragma unroll
        for (int k = 0; k < 32; ++k) {
            float2 m = *(const float2*)&sInT[k * 64 + 2 * ng];
            const float* wr = &sWn[k * 128 + og2 * 16];
            float4 w0 = *(const float4*)&wr[0];
            float4 w1 = *(const float4*)&wr[4];
            float4 w2 = *(const float4*)&wr[8];
            float4 w3 = *(const float4*)&wr[12];
            float ma[2] = { m.x, m.y };
            float wv[16] = { w0.x,w0.y,w0.z,w0.w, w1.x,w1.y,w1.z,w1.w,
                             w2.x,w2.y,w2.z,w2.w, w3.x,w3.y,w3.z,w3.w };
#pragma unroll
            for (int i = 0; i < 2; ++i)
#pragma unroll
                for (int j = 0; j < 16; ++j) acc2[i][j] += ma[i] * wv[j];
        }
    }

    float nbias[16];
#pragma unroll
    for (int j = 0; j < 16; ++j) nbias[j] = bn[og2 * 16 + j];

#pragma unroll
    for (int i = 0; i < 2; ++i) {
        int n = n0b + 2 * ng + i;
        if (n < N_NODES) {
            float* dst = out + (size_t)n * F_NODE + og2 * 16;
#pragma unroll
            for (int j = 0; j < 16; j += 4) {
                float4 v;
                v.x = fmaxf(acc2[i][j + 0] + nbias[j + 0], 0.f);
                v.y = fmaxf(acc2[i][j + 1] + nbias[j + 1], 0.f);
                v.z = fmaxf(acc2[i][j + 2] + nbias[j + 2], 0.f);
                v.w = fmaxf(acc2[i][j + 3] + nbias[j + 3], 0.f);
                *(float4*)(dst + j) = v;
            }
        }
    }
}

extern "C" void kernel_launch(void* const* d_in, const int* in_sizes, int n_in,
                              void* d_out, int out_size, void* d_ws, size_t ws_size,
                              hipStream_t stream) {
    const float* nf  = (const float*)d_in[0];
    const int*   idx = (const int*)d_in[1];
    const float* ef  = (const float*)d_in[2];
    const float* We  = (const float*)d_in[3];
    const float* be  = (const float*)d_in[4];
    const float* Wn  = (const float*)d_in[5];
    const float* bn  = (const float*)d_in[6];
    float* out = (float*)d_out;

    // ws: deg 0.2 MB + perm 2.4 MB + Q bf16 3.2 MB = 5.8 MB (confirmed safe)
    int* deg_cursor = (int*)d_ws;                          // 50000
    int* perm       = deg_cursor + N_NODES;                // 600000
    unsigned short* Q = (unsigned short*)(perm + N_EDGES); // [N][32] bf16

    hipMemsetAsync(deg_cursor, 0, (size_t)N_NODES * sizeof(int), stream);

    qcount_kernel<<<QBLOCKS + CBLOCKS, 256, 0, stream>>>(nf, We, idx, Q, deg_cursor);
    scan_kernel<<<1, 1024, 0, stream>>>(deg_cursor);
    scatter_kernel<<<CBLOCKS, 256, 0, stream>>>(idx, deg_cursor, perm);

    fused_kernel<<<QBLOCKS, 256, 0, stream>>>(
        nf, idx, ef, We, be, Wn, bn, perm, deg_cursor, Q, out);
}